// Round 12
// baseline (175.202 us; speedup 1.0000x reference)
//
#include <hip/hip_runtime.h>
#include <cstdint>

typedef __attribute__((ext_vector_type(8))) short short8;      // 8 bf16 = 4 VGPRs
typedef __attribute__((ext_vector_type(4))) float floatx4;     // 16x16 MFMA C/D frag
typedef __attribute__((ext_vector_type(16))) float floatx16;   // 32x32 MFMA C/D frag
typedef __attribute__((ext_vector_type(8))) _Float16 half8;    // 32x32x16 f16 A/B frag
typedef __attribute__((ext_vector_type(2))) _Float16 half2v;   // fdot2 operand

#define DEV __device__ __forceinline__

constexpr int NB = 2, Lseq = 2048, NH = 16, HD = 64, EMB = 1024;
// fold softmax scale (1/sqrt(1024)) and log2(e) into Wq so flash uses exp2
constexpr float QSCALE = 0.03125f * 1.4426950408889634f;

// pack two f32 -> two bf16 in one dword (round-half-up via bias, then v_perm)
DEV uint32_t pack2(float lo, float hi) {
  uint32_t a = __builtin_bit_cast(uint32_t, lo) + 0x8000u;
  uint32_t b = __builtin_bit_cast(uint32_t, hi) + 0x8000u;
  return __builtin_amdgcn_perm(b, a, 0x07060302);
}

DEV uint32_t packh2(float lo, float hi) {  // two f32 -> packed f16 dword
  return __builtin_bit_cast(uint32_t, __builtin_amdgcn_cvt_pkrtz(lo, hi));
}

DEV void gl_lds16(const void* g, void* l) {  // async global->LDS, 16B/lane
  __builtin_amdgcn_global_load_lds((const __attribute__((address_space(1))) void*)g,
                                   (__attribute__((address_space(3))) void*)l, 16, 0, 0);
}

// half-wave exchange: after call, x = [x_lo, y_lo], y = [x_hi, y_hi] (lane blocks of 32)
DEV void pl32(uint32_t& x, uint32_t& y) {
  typedef __attribute__((ext_vector_type(2))) unsigned int uint2v;
  uint2v r = __builtin_amdgcn_permlane32_swap(x, y, false, false);
  x = r[0];
  y = r[1];
}

// load 8 consecutive f32, scale, convert to a bf16 MFMA frag chunk
DEV short8 ld8bf(const float* p, float sc) {
  float4 u = *(const float4*)p;
  float4 v = *(const float4*)(p + 4);
  union { short8 s; uint32_t d[4]; } r;
  r.d[0] = pack2(u.x * sc, u.y * sc);
  r.d[1] = pack2(u.z * sc, u.w * sc);
  r.d[2] = pack2(v.x * sc, v.y * sc);
  r.d[3] = pack2(v.z * sc, v.w * sc);
  return r.s;
}

// ---------------- prep: Q/K/V projections (MFMA, LDS-free) + Wout cvt ----------------
__global__ __launch_bounds__(256) void prep_kernel(
    const float* __restrict__ values, const float* __restrict__ keysrc,
    const float* __restrict__ query, const float* __restrict__ Wv,
    const float* __restrict__ Wk, const float* __restrict__ Wq,
    const float* __restrict__ Wout,
    uint16_t* __restrict__ qp, uint16_t* __restrict__ kp,
    uint16_t* __restrict__ vp, uint16_t* __restrict__ wbf) {
  const int t = threadIdx.x, w = t >> 6, lane = t & 63;
  const int quad = lane >> 4, l16 = lane & 15;
  const int wid = blockIdx.x * 4 + w;
  const int mat = wid >> 10, sub = wid & 1023;

  if (mat == 3) {  // Wout f32 -> bf16
#pragma unroll
    for (int i = 0; i < 4; ++i) {
      int idx = sub * 256 + i * 64 + lane;
      float4 v = ((const float4*)Wout)[idx];
      uint2 p;
      p.x = pack2(v.x, v.y);
      p.y = pack2(v.z, v.w);
      ((uint2*)wbf)[idx] = p;
    }
    return;
  }

  floatx4 c[4][4];
#pragma unroll
  for (int i = 0; i < 4; ++i)
#pragma unroll
    for (int j = 0; j < 4; ++j) c[i][j] = floatx4{0.f, 0.f, 0.f, 0.f};

  if (mat < 2) {
    const float* src = mat ? keysrc : query;
    const float* W   = mat ? Wk : Wq;
    const float asc  = mat ? 1.f : QSCALE;
    uint16_t* dst    = mat ? kp : qp;
    const int R0 = sub * 64;
    short8 a[4][2], b[4][2];
#pragma unroll
    for (int dc = 0; dc < 2; ++dc) {
#pragma unroll
      for (int f = 0; f < 4; ++f) {
        a[f][dc] = ld8bf(W + (size_t)(f * 16 + l16) * 64 + dc * 32 + quad * 8, asc);
        b[f][dc] = ld8bf(src + (size_t)(R0 + f * 16 + l16) * 64 + dc * 32 + quad * 8, 1.f);
      }
    }
#pragma unroll
    for (int dc = 0; dc < 2; ++dc)
#pragma unroll
      for (int mf = 0; mf < 4; ++mf)
#pragma unroll
        for (int nf = 0; nf < 4; ++nf)
          c[mf][nf] = __builtin_amdgcn_mfma_f32_16x16x32_bf16(a[mf][dc], b[nf][dc], c[mf][nf], 0, 0, 0);
#pragma unroll
    for (int nf = 0; nf < 4; ++nf) {
      int r = R0 + nf * 16 + l16;
      int h = r & 15, l = (r >> 4) & 2047, n = r >> 15;
      uint16_t* drow = dst + ((size_t)(n * 16 + h) * 2048 + l) * 64;
#pragma unroll
      for (int mf = 0; mf < 4; ++mf) {
        uint2 pk;
        pk.x = pack2(c[mf][nf][0], c[mf][nf][1]);
        pk.y = pack2(c[mf][nf][2], c[mf][nf][3]);
        *(uint2*)(drow + mf * 16 + quad * 4) = pk;
      }
    }
  } else {
    const int nh = sub >> 5, L0 = (sub & 31) * 64;
    const int n = nh >> 4, h = nh & 15;
    short8 a[4][2], b[4][2];
#pragma unroll
    for (int dc = 0; dc < 2; ++dc) {
#pragma unroll
      for (int f = 0; f < 4; ++f) {
        a[f][dc] = ld8bf(values + (size_t)(n * 2048 + L0 + f * 16 + l16) * 1024 + h * 64 + dc * 32 + quad * 8, 1.f);
        b[f][dc] = ld8bf(Wv + (size_t)(f * 16 + l16) * 64 + dc * 32 + quad * 8, 1.f);
      }
    }
#pragma unroll
    for (int dc = 0; dc < 2; ++dc)
#pragma unroll
      for (int mf = 0; mf < 4; ++mf)
#pragma unroll
        for (int nf = 0; nf < 4; ++nf)
          c[mf][nf] = __builtin_amdgcn_mfma_f32_16x16x32_bf16(a[mf][dc], b[nf][dc], c[mf][nf], 0, 0, 0);
#pragma unroll
    for (int nf = 0; nf < 4; ++nf) {
      int d = nf * 16 + l16;
      uint16_t* drow = vp + ((size_t)nh * 64 + d) * 2048 + L0;
#pragma unroll
      for (int mf = 0; mf < 4; ++mf) {
        uint2 pk;
        pk.x = packh2(c[mf][nf][0], c[mf][nf][1]);
        pk.y = packh2(c[mf][nf][2], c[mf][nf][3]);
        *(uint2*)(drow + mf * 16 + quad * 4) = pk;
      }
    }
  }
}

// ---------------- Flash attention: 8-wave blocks, parallel-split kh combine ---------
// R11 main loop (32x32 MFMA, setprio, 2-buf + __syncthreads; waves 0-3 = kh0, 4-7 =
// kh1, 64 KB LDS, 2 blocks/CU = 16 waves/CU). Changes vs R11:
//  (1) lsum via v_dot2_f32_f16 on the already-packed f16 P dwords (8 dot2 replace the
//      15-add f32 tree; l now sums exactly the f16 P's PV consumes).
//  (2) parallel-split tail: each wave SHARES o[kh^1] (8 dwords to LDS) and KEEPS
//      o[kh]; after one barrier every wave merges its partner's (w^4) half, normalizes
//      and stores its own 32 d-columns of X (store formula = R11's with dt=kh).
//      Tail work per wave halves; no wave idles.
__global__ __launch_bounds__(512, 2) void flash_kernel(const uint16_t* __restrict__ qp,
                                                       const uint16_t* __restrict__ kp,
                                                       const uint16_t* __restrict__ vp,
                                                       uint16_t* __restrict__ xg) {
  constexpr int kbn = 16;
  __shared__ uint16_t Kt[2][2][64 * 64];   // [kh][buf] swizzled [key][d] bf16
  __shared__ uint16_t Vt[2][2][64 * 64];   // [kh][buf] swizzled [d][key] f16
  const int t = threadIdx.x;
  const int w = t >> 6, lane = t & 63, hi = lane >> 5, l32 = lane & 31;
  const int kh = w >> 2, wq = w & 3;
  const int nh = blockIdx.x, qt = blockIdx.y;
  const int q0w = qt * 128 + wq * 32;    // 32 q-rows per wave (kh pair shares q-range)
  const uint16_t* Qb = qp + (size_t)nh * Lseq * HD;
  const uint16_t* Kb = kp + (size_t)nh * Lseq * HD + (size_t)kh * 1024 * 64;
  const uint16_t* Vb = vp + (size_t)nh * HD * Lseq;
  const int vcol0 = kh * 1024;
  const int srow = lane >> 3, sc8 = (lane & 7) ^ (lane >> 3);  // staging swizzle base

  // Q B-frags (32x32x16: lane holds B[k=hi*8+i][col=l32], k = d within dc-slice)
  short8 bq[4];
#pragma unroll
  for (int dc = 0; dc < 4; ++dc)
    bq[dc] = *(const short8*)(Qb + (size_t)(q0w + l32) * 64 + dc * 16 + hi * 8);

  floatx16 o[2];        // O^T frags (dt=0,1)
  float lsum = 0.f;     // l partial via fdot2 over packed f16 P's
#pragma unroll
  for (int r = 0; r < 16; ++r) { o[0][r] = 0.f; o[1][r] = 0.f; }
  const half2v one2 = {(_Float16)1.0f, (_Float16)1.0f};

  auto stage = [&](int tile, int buf) {  // 4 DMA instrs/wave (8 row-groups / 4 waves)
#pragma unroll
    for (int i = 0; i < 2; ++i) {
      int r0 = wq * 16 + i * 8;
      int sc = sc8 ^ ((wq * 2 + i) & 3);  // (row>>3)&3 for rows r0..r0+7
      gl_lds16(Kb + (size_t)tile * 4096 + (r0 + srow) * 64 + sc * 8, &Kt[kh][buf][r0 * 64]);
      gl_lds16(Vb + (size_t)(r0 + srow) * Lseq + vcol0 + tile * 64 + sc * 8, &Vt[kh][buf][r0 * 64]);
    }
  };

  stage(0, 0);

  for (int kb = 0; kb < kbn; ++kb) {
    __syncthreads();
    const int cur = kb & 1;
    if (kb + 1 < kbn) stage(kb + 1, cur ^ 1);

#pragma unroll
    for (int kt = 0; kt < 2; ++kt) {
      // S^T(32keys x 32q) = K_tile · Q^T, K=16 per step over d=64
      floatx16 s;
#pragma unroll
      for (int r = 0; r < 16; ++r) s[r] = 0.f;
      const int krow = kt * 32 + l32;
      const int ksw = (krow & 7) ^ ((krow >> 3) & 3);
      __builtin_amdgcn_s_setprio(1);
#pragma unroll
      for (int dc = 0; dc < 4; ++dc) {
        short8 ak = *(const short8*)(&Kt[kh][cur][krow * 64 + (((dc << 1) | hi) ^ ksw) * 8]);
        s = __builtin_amdgcn_mfma_f32_32x32x16_bf16(ak, bq[dc], s, 0, 0, 0);
      }
      __builtin_amdgcn_s_setprio(0);

      // p = exp2(s); pack to f16 pairs; lsum via fdot2 on the packed dwords
      float ex[16];
#pragma unroll
      for (int r = 0; r < 16; ++r) ex[r] = __builtin_amdgcn_exp2f(s[r]);
      uint32_t a0 = packh2(ex[0], ex[1]);
      uint32_t a1 = packh2(ex[2], ex[3]);
      uint32_t b0 = packh2(ex[4], ex[5]);
      uint32_t b1 = packh2(ex[6], ex[7]);
      uint32_t c0 = packh2(ex[8], ex[9]);
      uint32_t c1 = packh2(ex[10], ex[11]);
      uint32_t d0 = packh2(ex[12], ex[13]);
      uint32_t d1 = packh2(ex[14], ex[15]);
      lsum = __builtin_amdgcn_fdot2(__builtin_bit_cast(half2v, a0), one2, lsum, false);
      lsum = __builtin_amdgcn_fdot2(__builtin_bit_cast(half2v, a1), one2, lsum, false);
      lsum = __builtin_amdgcn_fdot2(__builtin_bit_cast(half2v, b0), one2, lsum, false);
      lsum = __builtin_amdgcn_fdot2(__builtin_bit_cast(half2v, b1), one2, lsum, false);
      lsum = __builtin_amdgcn_fdot2(__builtin_bit_cast(half2v, c0), one2, lsum, false);
      lsum = __builtin_amdgcn_fdot2(__builtin_bit_cast(half2v, c1), one2, lsum, false);
      lsum = __builtin_amdgcn_fdot2(__builtin_bit_cast(half2v, d0), one2, lsum, false);
      lsum = __builtin_amdgcn_fdot2(__builtin_bit_cast(half2v, d1), one2, lsum, false);

      pl32(a0, b0); pl32(a1, b1); pl32(c0, d0); pl32(c1, d1);
      union { half8 h; uint32_t u[4]; } f0, f1;
      f0.u[0] = a0; f0.u[1] = a1; f0.u[2] = b0; f0.u[3] = b1;  // keys kt*32 + 0..15
      f1.u[0] = c0; f1.u[1] = c1; f1.u[2] = d0; f1.u[3] = d1;  // keys kt*32 + 16..31

      // O^T += V^T · P
      __builtin_amdgcn_s_setprio(1);
#pragma unroll
      for (int dt = 0; dt < 2; ++dt) {
        const int vrow = dt * 32 + l32;
        const int vsw = (vrow & 7) ^ ((vrow >> 3) & 3);
        half8 av0 = *(const half8*)(&Vt[kh][cur][vrow * 64 + ((kt * 4 + hi) ^ vsw) * 8]);
        o[dt] = __builtin_amdgcn_mfma_f32_32x32x16_f16(av0, f0.h, o[dt], 0, 0, 0);
        half8 av1 = *(const half8*)(&Vt[kh][cur][vrow * 64 + ((kt * 4 + 2 + hi) ^ vsw) * 8]);
        o[dt] = __builtin_amdgcn_mfma_f32_32x32x16_f16(av1, f1.h, o[dt], 0, 0, 0);
      }
      __builtin_amdgcn_s_setprio(0);
    }
  }

  // finish l: add the other hi-half's partial (lanes l32 and l32+32 share q = l32)
  {
    uint32_t sx = __builtin_bit_cast(uint32_t, lsum), sy = sx;
    pl32(sx, sy);
    float oth = __builtin_bit_cast(float, (lane < 32) ? sy : sx);
    lsum += oth;
  }

  // ---- parallel-split kh combine (LDS scratch reuses Kt/Vt after last tile) ----
  // scr layout [j][wave][lane]: contiguous per (j,wave) -> 2-way bank alias = free.
  uint32_t* scr = (uint32_t*)&Kt[0][0][0];   // 8 dwords/lane * 8 waves * 64 = 16 KB
  float* lscr = (float*)&Vt[0][0][0];        // 8 waves * 32 floats = 1 KB
  __syncthreads();                           // all LDS reads of last tile complete

  auto dump_give = [&](const floatx16& og) {  // share the dt = kh^1 half
#pragma unroll
    for (int j = 0; j < 8; ++j)
      scr[j * 512 + w * 64 + lane] = packh2(og[2 * j], og[2 * j + 1]);
  };
  if (kh == 0) dump_give(o[1]); else dump_give(o[0]);
  if (hi == 0) lscr[w * 32 + l32] = lsum;
  __syncthreads();

  auto merge_store = [&](const floatx16& ok) {  // merge + write own dt = kh half
    const float lpart = lscr[(w ^ 4) * 32 + l32];
    const float inv = __builtin_amdgcn_rcpf(lsum + lpart);
    const int nn = nh >> 4, h = nh & 15;
    uint16_t* xr = xg + ((size_t)(nn * 2048 + q0w + l32)) * 1024 + h * 64 + kh * 32;
#pragma unroll
    for (int rg = 0; rg < 4; ++rg) {
      union { uint32_t u; _Float16 hh[2]; } u0, u1;
      u0.u = scr[(rg * 2) * 512 + (w ^ 4) * 64 + lane];
      u1.u = scr[(rg * 2 + 1) * 512 + (w ^ 4) * 64 + lane];
      float s0 = ok[rg * 4 + 0] + (float)u0.hh[0];
      float s1 = ok[rg * 4 + 1] + (float)u0.hh[1];
      float s2 = ok[rg * 4 + 2] + (float)u1.hh[0];
      float s3 = ok[rg * 4 + 3] + (float)u1.hh[1];
      uint2 pk;
      pk.x = pack2(s0 * inv, s1 * inv);
      pk.y = pack2(s2 * inv, s3 * inv);
      *(uint2*)(xr + rg * 8 + 4 * hi) = pk;
    }
  };
  if (kh == 0) merge_store(o[0]); else merge_store(o[1]);
}

// ---------------- out GEMM: out = X @ Wout^T + bias, 64x128 tiles -------------------
// (R9 verbatim.) Counted-vmcnt 3-buffer schedule (6 DMAs/tile/wave -> vmcnt(6)).
__global__ __launch_bounds__(256, 2) void out_gemm(const uint16_t* __restrict__ Xg,
                                                   const uint16_t* __restrict__ Wb,
                                                   const float* __restrict__ bias,
                                                   float* __restrict__ out) {
  __shared__ uint16_t Xt[3][64 * 64];
  __shared__ uint16_t Wt[3][128 * 64];
  const int t = threadIdx.x, w = t >> 6, lane = t & 63, quad = lane >> 4, l16 = lane & 15;
  const int m0 = blockIdx.x * 64, o0 = blockIdx.y * 128;
  const int srow = lane >> 3, sc8 = (lane & 7) ^ (lane >> 3);

  floatx4 acc[8];
#pragma unroll
  for (int j = 0; j < 8; ++j) acc[j] = floatx4{0.f, 0.f, 0.f, 0.f};

  auto stage = [&](int buf, int kt) {  // 6 DMA instrs/wave
#pragma unroll
    for (int i = 0; i < 2; ++i) {   // X: 16 rows/wave
      int r0 = w * 16 + i * 8;
      gl_lds16(Xg + (size_t)(m0 + r0 + srow) * 1024 + kt * 64 + sc8 * 8, &Xt[buf][r0 * 64]);
    }
#pragma unroll
    for (int i = 0; i < 4; ++i) {   // W: 32 rows/wave
      int r0 = w * 32 + i * 8;
      gl_lds16(Wb + (size_t)(o0 + r0 + srow) * 1024 + kt * 64 + sc8 * 8, &Wt[buf][r0 * 64]);
    }
  };

  stage(0, 0);
  stage(1, 1);

  int cur = 0;
  for (int kt = 0; kt < 16; ++kt) {
    if (kt + 1 < 16) asm volatile("s_waitcnt vmcnt(6)" ::: "memory");
    else             asm volatile("s_waitcnt vmcnt(0)" ::: "memory");
    __builtin_amdgcn_s_barrier();
    if (kt + 2 < 16) {
      int tgt = cur + 2; if (tgt >= 3) tgt -= 3;
      stage(tgt, kt + 2);
    }
#pragma unroll
    for (int kc = 0; kc < 2; ++kc) {
      int ra = w * 16 + l16;
      short8 a = *(const short8*)(&Xt[cur][ra * 64 + ((kc * 4 + quad) ^ (ra & 7)) * 8]);
#pragma unroll
      for (int nf = 0; nf < 8; ++nf) {
        int rb = nf * 16 + l16;
        short8 b = *(const short8*)(&Wt[cur][rb * 64 + ((kc * 4 + quad) ^ (rb & 7)) * 8]);
        acc[nf] = __builtin_amdgcn_mfma_f32_16x16x32_bf16(a, b, acc[nf], 0, 0, 0);
      }
    }
    asm volatile("s_waitcnt lgkmcnt(0)" ::: "memory");
    cur = (cur + 1 == 3) ? 0 : cur + 1;
  }

#pragma unroll
  for (int nf = 0; nf < 8; ++nf) {
    float bv = bias[o0 + nf * 16 + l16];
#pragma unroll
    for (int r = 0; r < 4; ++r)
      out[(size_t)(m0 + w * 16 + quad * 4 + r) * 1024 + o0 + nf * 16 + l16] = acc[nf][r] + bv;
  }
}

extern "C" void kernel_launch(void* const* d_in, const int* in_sizes, int n_in,
                              void* d_out, int out_size, void* d_ws, size_t ws_size,
                              hipStream_t stream) {
  const float* values = (const float*)d_in[0];
  const float* keys   = (const float*)d_in[1];
  const float* query  = (const float*)d_in[2];
  const float* Wv     = (const float*)d_in[3];
  const float* Wk     = (const float*)d_in[4];
  const float* Wq     = (const float*)d_in[5];
  const float* Wout   = (const float*)d_in[6];
  const float* bout   = (const float*)d_in[7];
  float* out = (float*)d_out;
  (void)ws_size;

  uint16_t* ws  = (uint16_t*)d_ws;
  uint16_t* qp  = ws;                                // 8 MB bf16 [nh][l][d]
  uint16_t* kp  = ws + (size_t)4194304;              // 8 MB bf16 [nh][l][d]
  uint16_t* vp  = ws + (size_t)8388608;              // 8 MB f16  [nh][d][l]
  uint16_t* wbf = ws + (size_t)12582912;             // 2 MB bf16 Wout
  uint16_t* xp  = ws + (size_t)13631488;             // 8 MB bf16 X = normalized attn out

  prep_kernel<<<dim3(1024), dim3(256), 0, stream>>>(values, keys, query, Wv, Wk, Wq, Wout,
                                                    qp, kp, vp, wbf);
  flash_kernel<<<dim3(32, 16), dim3(512), 0, stream>>>(qp, kp, vp, xp);
  out_gemm<<<dim3(64, 8), dim3(256), 0, stream>>>(xp, wbf, bout, out);
}